// Round 9
// baseline (304.382 us; speedup 1.0000x reference)
//
#include <hip/hip_runtime.h>

// Model dims (fixed by the reference)
#define S_DIM   6
#define H_DIM   20
#define F_INN   8
#define N_OUTC  20
#define G_DIM   32
#define D1_DIM  16
#define NGRAPH  512

typedef short short8 __attribute__((ext_vector_type(8)));
typedef float floatx4 __attribute__((ext_vector_type(4)));

__device__ __forceinline__ unsigned short f2bf(float f) {
    unsigned u = __float_as_uint(f);
    return (unsigned short)((u + 0x8000u) >> 16);   // RTN (ties up)
}
__device__ __forceinline__ float bf2f(unsigned short s) {
    return __uint_as_float(((unsigned)s) << 16);
}

// ---------------------------------------------------------------------------
// 1) loc: per-edge local slot within its row (1 int atomic/edge). cnt -> deg.
// ---------------------------------------------------------------------------
__global__ __launch_bounds__(256) void loc_kernel(
    const int* __restrict__ ei, int E, int* __restrict__ cnt,
    int* __restrict__ loc)
{
    int i = blockIdx.x * 256 + threadIdx.x;
    if (i >= E) return;
    loc[i] = atomicAdd(&cnt[ei[i]], 1);
}

// ---------------------------------------------------------------------------
// 2a) Per-block sums of deg (coalesced)
// ---------------------------------------------------------------------------
__global__ __launch_bounds__(256) void scanA_kernel(
    const int* __restrict__ deg, int N, int* __restrict__ bsum)
{
    int i = blockIdx.x * 256 + threadIdx.x;
    int v = (i < N) ? deg[i] : 0;
#pragma unroll
    for (int d = 1; d < 64; d <<= 1) v += __shfl_down(v, d, 64);
    __shared__ int ws[4];
    int wid = threadIdx.x >> 6;
    if ((threadIdx.x & 63) == 0) ws[wid] = v;
    __syncthreads();
    if (threadIdx.x == 0) bsum[blockIdx.x] = ws[0] + ws[1] + ws[2] + ws[3];
}

// ---------------------------------------------------------------------------
// 2b) Apply: block offset from bsum, block-local scan -> rowptr; dinv
// ---------------------------------------------------------------------------
__global__ __launch_bounds__(256) void scanC_kernel(
    const int* __restrict__ deg, int N, const int* __restrict__ bsum, int nbl,
    int E, int* __restrict__ rowptr, float* __restrict__ dinv)
{
    __shared__ int ws[4];
    __shared__ int sboff;
    int t = threadIdx.x;
    {
        int v = (t < nbl && t < blockIdx.x) ? bsum[t] : 0;
#pragma unroll
        for (int d = 1; d < 64; d <<= 1) v += __shfl_down(v, d, 64);
        int wid = t >> 6;
        if ((t & 63) == 0) ws[wid] = v;
        __syncthreads();
        if (t == 0) sboff = ws[0] + ws[1] + ws[2] + ws[3];
        __syncthreads();
    }

    int i = blockIdx.x * 256 + t;
    int d0 = (i < N) ? deg[i] : 0;
    int v = d0;
#pragma unroll
    for (int d = 1; d < 64; d <<= 1) {
        int u = __shfl_up(v, d, 64);
        if ((t & 63) >= d) v += u;
    }
    __shared__ int ws2[4];
    int wid = t >> 6;
    if ((t & 63) == 63) ws2[wid] = v;
    __syncthreads();
    int woff = 0;
    for (int w = 0; w < wid; ++w) woff += ws2[w];
    if (i < N) {
        rowptr[i] = sboff + woff + v - d0;
        dinv[i] = rsqrtf((float)d0 + 1.0f);
    }
    if (blockIdx.x == 0 && t == 0) rowptr[N] = E;
}

// ---------------------------------------------------------------------------
// 3) Build CSR slot arrays (no atomics: p = rowptr[r] + loc[i])
// ---------------------------------------------------------------------------
__global__ __launch_bounds__(256) void build_kernel(
    const int* __restrict__ ei, int E, const int* __restrict__ rowptr,
    const int* __restrict__ loc,
    int* __restrict__ eid_at_slot, int* __restrict__ col_sorted)
{
    int i = blockIdx.x * 256 + threadIdx.x;
    if (i >= E) return;
    int p = rowptr[ei[i]] + loc[i];
    eid_at_slot[p] = i;
    col_sorted[p] = ei[E + i];
}

// ---------------------------------------------------------------------------
// 4) ECC: h1 on VALU (fp32) -> bf16 LDS; h2 via MFMA (K=32 single step);
//    einsum via MFMA (K=192); segmented row reduction. CSR order.
//    LDS: B3 12K + B2 2K + h1b 12K + xb 4K + h2bs 2.5K = 32.5 KB;
//    lmsg fp32[256][20] aliases [0, 20480) after MFMA phases.
// ---------------------------------------------------------------------------
__global__ __launch_bounds__(256) void ecc_mfma_kernel(
    const float* __restrict__ e, const float* __restrict__ x,
    const int* __restrict__ eid_at_slot, const int* __restrict__ col_sorted,
    const int* __restrict__ rowptr, int N, int E,
    const float* __restrict__ w1, const float* __restrict__ b1,
    const float* __restrict__ w2, const float* __restrict__ b2,
    const float* __restrict__ w3, const float* __restrict__ b3,
    float* __restrict__ agg)
{
    __shared__ char smem[33280];
    __shared__ int rbounds[2];
    unsigned short* B3l  = (unsigned short*)smem;              // [0,12288)
    unsigned short* B2l  = (unsigned short*)(smem + 12288);    // [12288,14336)
    unsigned short* h1b  = (unsigned short*)(smem + 14336);    // 256*24*2 = 12288
    unsigned short* xb   = (unsigned short*)(smem + 26624);    // 256*8*2  = 4096
    unsigned short* h2bs = (unsigned short*)(smem + 30720);    // 4*16*20*2= 2560
    float* lmsg = (float*)smem;                                // aliases [0,20480)

    int t = threadIdx.x;
    int j0 = blockIdx.x * 256;
    int jend = min(j0 + 256, E);
    int j = j0 + t;

    if (t < 2) {
        int s = (t == 0) ? j0 : (jend - 1);
        int lo = 0, hi = N - 1;
        while (lo < hi) {
            int m = (lo + hi + 1) >> 1;
            if (rowptr[m] <= s) lo = m; else hi = m - 1;
        }
        rbounds[t] = lo;
    }

    // ---- stage B3 (einsum weights), fragment layout [s][nt][quad][n][j] ----
    for (int idx = t; idx < 6144; idx += 256) {
        int jj   = idx & 7;
        int n    = (idx >> 3) & 15;
        int quad = (idx >> 7) & 3;
        int nt   = (idx >> 9) & 1;
        int s    = idx >> 10;
        int K = 32 * s + quad * 8 + jj;
        int o = n + 16 * nt;
        float v = 0.0f;
        if (o < N_OUTC) {
            if (K < 160)      v = w3[(K >> 3) * 160 + (K & 7) * N_OUTC + o];
            else if (K < 168) v = b3[(K - 160) * N_OUTC + o];
        }
        B3l[idx] = f2bf(v);
    }
    // ---- stage B2 (h2-layer weights), same generator, single k-step ----
    for (int idx = t; idx < 1024; idx += 256) {
        int jj   = idx & 7;
        int n    = (idx >> 3) & 15;
        int quad = (idx >> 7) & 3;
        int nt   = (idx >> 9) & 1;
        int K = quad * 8 + jj;
        int o = n + 16 * nt;
        float v = (o < N_OUTC && K < H_DIM) ? w2[K * H_DIM + o] : 0.0f;
        B2l[idx] = f2bf(v);
    }

    // ---- per-edge: h1 (fp32 VALU) -> h1b bf16; x[col] -> xb bf16 ----
    if (j < E) {
        int i = eid_at_slot[j];
        int c = col_sorted[j];

        float ef[S_DIM];
#pragma unroll
        for (int s = 0; s < S_DIM; ++s) ef[s] = e[(size_t)i * S_DIM + s];

        float h1[H_DIM];
#pragma unroll
        for (int jj = 0; jj < H_DIM; ++jj) {
            float a = b1[jj];
#pragma unroll
            for (int s = 0; s < S_DIM; ++s) a = fmaf(ef[s], w1[s * H_DIM + jj], a);
            h1[jj] = fmaxf(a, 0.0f);
        }

        short8 p0, p1, p2;
#pragma unroll
        for (int k = 0; k < 8; ++k) p0[k] = (short)f2bf(h1[k]);
#pragma unroll
        for (int k = 0; k < 8; ++k) p1[k] = (short)f2bf(h1[8 + k]);
#pragma unroll
        for (int k = 0; k < 8; ++k) p2[k] = (k < 4) ? (short)f2bf(h1[16 + k]) : (short)0;
        short8* hdst = (short8*)&h1b[t * 24];
        hdst[0] = p0; hdst[1] = p1; hdst[2] = p2;

        const float4* xp = (const float4*)&x[(size_t)c * F_INN];
        float4 xa = xp[0], xb4 = xp[1];
        float xf[F_INN] = {xa.x, xa.y, xa.z, xa.w, xb4.x, xb4.y, xb4.z, xb4.w};
        short8 xv;
#pragma unroll
        for (int f = 0; f < F_INN; ++f) xv[f] = (short)f2bf(xf[f]);
        *(short8*)&xb[t * 8] = xv;
    } else {
        short8 z = {0, 0, 0, 0, 0, 0, 0, 0};
        short8* hdst = (short8*)&h1b[t * 24];
        hdst[0] = z; hdst[1] = z; hdst[2] = z;
        *(short8*)&xb[t * 8] = z;
    }
    __syncthreads();

    // ---- fragment loads ----
    int lane = t & 63;
    int quad = lane >> 4;
    int n = lane & 15;
    int w = t >> 6;

    short8 Bw2_0 = *(const short8*)&B2l[((0 * 4 + quad) * 16 + n) * 8];
    short8 Bw2_1 = *(const short8*)&B2l[((1 * 4 + quad) * 16 + n) * 8];
    short8 Bf[12];
#pragma unroll
    for (int s = 0; s < 6; ++s)
#pragma unroll
        for (int nt = 0; nt < 2; ++nt)
            Bf[s * 2 + nt] = *(const short8*)&B3l[((((s * 2 + nt) * 4 + quad) * 16 + n) * 8)];

    float b2lo = b2[n];
    float b2hi = (n < 4) ? b2[16 + n] : 0.0f;
    unsigned short* hrow = &h2bs[w * 16 * N_OUTC];   // per-wave tile buffer
    const short8 z8 = {0, 0, 0, 0, 0, 0, 0, 0};

    // ---- per-tile pipeline: h2-MFMA -> relu -> einsum MFMAs (intra-wave) ----
    floatx4 acc0s[4], acc1s[4];
#pragma unroll
    for (int T = 0; T < 4; ++T) {
        int base = w * 64 + T * 16;
        int m = base + n;                     // A-row (edge-local in block)

        // h2 = relu(h1 @ w2 + b2): one k-step (K=32, rows 20..31 zero)
        short8 A1 = (quad < 3) ? *(const short8*)&h1b[m * 24 + quad * 8] : z8;
        floatx4 c0 = {0.f, 0.f, 0.f, 0.f};
        floatx4 c1 = {0.f, 0.f, 0.f, 0.f};
        c0 = __builtin_amdgcn_mfma_f32_16x16x32_bf16(A1, Bw2_0, c0, 0, 0, 0);
        c1 = __builtin_amdgcn_mfma_f32_16x16x32_bf16(A1, Bw2_1, c1, 0, 0, 0);
#pragma unroll
        for (int r = 0; r < 4; ++r) {
            int lm = quad * 4 + r;            // local row within tile
            hrow[lm * N_OUTC + n] = f2bf(fmaxf(c0[r] + b2lo, 0.0f));
            if (n < 4) hrow[lm * N_OUTC + 16 + n] = f2bf(fmaxf(c1[r] + b2hi, 0.0f));
        }

        // einsum: A[m][K] = h2[m][K>>3] * x[m][K&7]  (K<160), rows 160-167 = x
        const short8 xv8 = *(const short8*)&xb[m * 8];
        float xfl[F_INN];
#pragma unroll
        for (int jj = 0; jj < F_INN; ++jj) xfl[jj] = bf2f((unsigned short)xv8[jj]);

        floatx4 acc0 = {0.f, 0.f, 0.f, 0.f};
        floatx4 acc1 = {0.f, 0.f, 0.f, 0.f};
#pragma unroll
        for (int s = 0; s < 6; ++s) {
            short8 A = z8;
            if (s < 5) {
                float h = bf2f(hrow[n * N_OUTC + 4 * s + quad]);
#pragma unroll
                for (int jj = 0; jj < F_INN; ++jj)
                    A[jj] = (short)f2bf(h * xfl[jj]);
            } else if (quad == 0) {
                A = xv8;
            }
            acc0 = __builtin_amdgcn_mfma_f32_16x16x32_bf16(A, Bf[s * 2 + 0], acc0, 0, 0, 0);
            acc1 = __builtin_amdgcn_mfma_f32_16x16x32_bf16(A, Bf[s * 2 + 1], acc1, 0, 0, 0);
        }
        acc0s[T] = acc0;
        acc1s[T] = acc1;
    }
    __syncthreads();   // all staging reads done -> lmsg may alias

    // ---- C-write: col = n (+16 for acc1), row = base + quad*4 + r ----
#pragma unroll
    for (int T = 0; T < 4; ++T) {
        int base = w * 64 + T * 16;
#pragma unroll
        for (int r = 0; r < 4; ++r) {
            int row = base + quad * 4 + r;
            lmsg[row * N_OUTC + n] = acc0s[T][r];
            if (n < 4) lmsg[row * N_OUTC + 16 + n] = acc1s[T][r];
        }
    }
    __syncthreads();

    // ---- segmented row reduction into agg ----
    int r0 = rbounds[0], r1 = rbounds[1];
    int work = (r1 - r0 + 1) * 5;
    for (int ww = t; ww < work; ww += 256) {
        int row = r0 + ww / 5;
        int q = ww - (ww / 5) * 5;
        int a0 = rowptr[row], a1 = rowptr[row + 1];
        int s0 = max(a0, j0), s1 = min(a1, jend);
        float4 acc = make_float4(0.f, 0.f, 0.f, 0.f);
        for (int s = s0; s < s1; ++s) {
            const float4 v = *(const float4*)&lmsg[(s - j0) * N_OUTC + q * 4];
            acc.x += v.x; acc.y += v.y; acc.z += v.z; acc.w += v.w;
        }
        float* dst = &agg[(size_t)row * N_OUTC + q * 4];
        if (a0 >= j0 && a1 <= jend) {
            *(float4*)dst = acc;
        } else {
            unsafeAtomicAdd(dst + 0, acc.x);
            unsafeAtomicAdd(dst + 1, acc.y);
            unsafeAtomicAdd(dst + 2, acc.z);
            unsafeAtomicAdd(dst + 3, acc.w);
        }
    }
}

// ---------------------------------------------------------------------------
// 5) Node transform: x1 = relu(agg + x@root + b);
//    hws1 = bf16( dinv * (x1 @ gcn1_w) )
// ---------------------------------------------------------------------------
__global__ __launch_bounds__(256) void node1_kernel(
    const float* __restrict__ agg, const float* __restrict__ x,
    const float* __restrict__ dinv, int N,
    const float* __restrict__ root, const float* __restrict__ eb,
    const float* __restrict__ g1w,
    unsigned short* __restrict__ hws1)
{
    int n = blockIdx.x * 256 + threadIdx.x;
    if (n >= N) return;

    const float4* xp = (const float4*)&x[(size_t)n * F_INN];
    float4 xa = xp[0], xb = xp[1];
    float xf[F_INN] = {xa.x, xa.y, xa.z, xa.w, xb.x, xb.y, xb.z, xb.w};

    float x1[N_OUTC];
#pragma unroll
    for (int o = 0; o < N_OUTC; ++o) {
        float a = agg[(size_t)n * N_OUTC + o] + eb[o];
#pragma unroll
        for (int f = 0; f < F_INN; ++f) a = fmaf(xf[f], root[f * N_OUTC + o], a);
        x1[o] = fmaxf(a, 0.0f);
    }

    float di = dinv[n];
#pragma unroll
    for (int q = 0; q < 4; ++q) {
        short8 o8;
#pragma unroll
        for (int u = 0; u < 8; ++u) {
            int g = q * 8 + u;
            float a = 0.0f;
#pragma unroll
            for (int o = 0; o < N_OUTC; ++o) a = fmaf(x1[o], g1w[o * G_DIM + g], a);
            o8[u] = (short)f2bf(a * di);
        }
        *(short8*)&hws1[(size_t)n * G_DIM + q * 8] = o8;
    }
}

// ---------------------------------------------------------------------------
// 6) GCN gather on pre-scaled bf16 features. Thread = (node, chunk of 4);
//    each thread handles 8 channels (one 16B bf16 load per neighbor).
// ---------------------------------------------------------------------------
template<bool DO_MATMUL>
__global__ __launch_bounds__(256) void gcn_gather_kernel(
    const unsigned short* __restrict__ hws, const int* __restrict__ rowptr,
    const int* __restrict__ col_sorted, const float* __restrict__ dinv, int N,
    const float* __restrict__ bias, const float* __restrict__ w2,
    unsigned short* __restrict__ outbuf)
{
    __shared__ float x2s[64][33];
    __shared__ float w2s[G_DIM * G_DIM];

    int t = threadIdx.x;
    int nl = t >> 2;
    int q = t & 3;
    int n = blockIdx.x * 64 + nl;

    if (DO_MATMUL) {
        ((float4*)w2s)[t] = ((const float4*)w2)[t];
    }

    float xo[8];
    float di = 0.0f;
    if (n < N) {
        di = dinv[n];
        int j0 = rowptr[n], j1 = rowptr[n + 1];
        short8 sv = *(const short8*)&hws[(size_t)n * G_DIM + q * 8];
        float s[8];
#pragma unroll
        for (int k = 0; k < 8; ++k) s[k] = bf2f((unsigned short)sv[k]);
        for (int j = j0; j < j1; ++j) {
            int c = col_sorted[j];
            short8 v = *(const short8*)&hws[(size_t)c * G_DIM + q * 8];
#pragma unroll
            for (int k = 0; k < 8; ++k) s[k] += bf2f((unsigned short)v[k]);
        }
#pragma unroll
        for (int k = 0; k < 8; ++k)
            xo[k] = fmaxf(fmaf(di, s[k], bias[q * 8 + k]), 0.0f);
    } else {
#pragma unroll
        for (int k = 0; k < 8; ++k) xo[k] = 0.0f;
    }

    if (DO_MATMUL) {
#pragma unroll
        for (int k = 0; k < 8; ++k) x2s[nl][q * 8 + k] = xo[k];
        __syncthreads();
        if (n < N) {
            float a[8];
#pragma unroll
            for (int k = 0; k < 8; ++k) a[k] = 0.0f;
#pragma unroll
            for (int g = 0; g < G_DIM; ++g) {
                float xv = x2s[nl][g];
#pragma unroll
                for (int k = 0; k < 8; ++k)
                    a[k] = fmaf(xv, w2s[g * G_DIM + q * 8 + k], a[k]);
            }
            short8 o8;
#pragma unroll
            for (int k = 0; k < 8; ++k) o8[k] = (short)f2bf(a[k] * di);
            *(short8*)&outbuf[(size_t)n * G_DIM + q * 8] = o8;
        }
    } else {
        if (n < N) {
            short8 o8;
#pragma unroll
            for (int k = 0; k < 8; ++k) o8[k] = (short)f2bf(xo[k]);
            *(short8*)&outbuf[(size_t)n * G_DIM + q * 8] = o8;
        }
    }
}

// ---------------------------------------------------------------------------
// 7) Pool + head fused (x3 is bf16)
// ---------------------------------------------------------------------------
__global__ __launch_bounds__(256) void pool_head_kernel(
    const unsigned short* __restrict__ x3, const int* __restrict__ seg, int N,
    const float* __restrict__ d1w, const float* __restrict__ d1b,
    const float* __restrict__ d2w, const float* __restrict__ d2b,
    float* __restrict__ out)
{
    __shared__ float red[8][G_DIM];
    __shared__ float pvec[G_DIM];
    __shared__ int bounds[2];
    int g = blockIdx.x;
    int t = threadIdx.x;
    if (t < 2) {
        int target = g + t;
        int lo = 0, hi = N;
        while (lo < hi) {
            int m = (lo + hi) >> 1;
            if (seg[m] < target) lo = m + 1; else hi = m;
        }
        bounds[t] = lo;
    }
    __syncthreads();
    int n0 = bounds[0], n1 = bounds[1];
    int ch = t & (G_DIM - 1);
    int slice = t >> 5;
    float a = 0.0f;
    for (int n = n0 + slice; n < n1; n += 8)
        a += bf2f(x3[(size_t)n * G_DIM + ch]);
    red[slice][ch] = a;
    __syncthreads();
    if (slice == 0) {
        float s = red[0][ch];
#pragma unroll
        for (int k = 1; k < 8; ++k) s += red[k][ch];
        pvec[ch] = s;
    }
    __syncthreads();
    if (t < 64) {
        float acc = 0.0f;
        if (t < D1_DIM) {
            float tj = d1b[t];
#pragma unroll
            for (int gg = 0; gg < G_DIM; ++gg)
                tj = fmaf(pvec[gg], d1w[gg * D1_DIM + t], tj);
            acc = tj * d2w[t];
        }
#pragma unroll
        for (int d = 1; d < D1_DIM; d <<= 1) acc += __shfl_down(acc, d, 64);
        if (t == 0) out[g] = acc + d2b[0];
    }
}

// ---------------------------------------------------------------------------
extern "C" void kernel_launch(void* const* d_in, const int* in_sizes, int n_in,
                              void* d_out, int out_size, void* d_ws, size_t ws_size,
                              hipStream_t stream)
{
    const float* x    = (const float*)d_in[0];
    const float* e    = (const float*)d_in[1];
    const int*   ei   = (const int*)d_in[2];
    const int*   seg  = (const int*)d_in[3];
    const float* w1   = (const float*)d_in[4];
    const float* b1   = (const float*)d_in[5];
    const float* w2   = (const float*)d_in[6];
    const float* b2   = (const float*)d_in[7];
    const float* w3   = (const float*)d_in[8];
    const float* b3   = (const float*)d_in[9];
    const float* root = (const float*)d_in[10];
    const float* eb   = (const float*)d_in[11];
    const float* g1w  = (const float*)d_in[12];
    const float* g1b  = (const float*)d_in[13];
    const float* g2w  = (const float*)d_in[14];
    const float* g2b  = (const float*)d_in[15];
    const float* d1w  = (const float*)d_in[16];
    const float* d1b  = (const float*)d_in[17];
    const float* d2w  = (const float*)d_in[18];
    const float* d2b  = (const float*)d_in[19];

    const int N = in_sizes[3];            // 50000
    const int E = in_sizes[1] / S_DIM;    // 800000
    float* out = (float*)d_out;

    const int nbl = (N + 255) / 256;      // 196 (<= 256 for scanC)
    const int ebl = (E + 255) / 256;

    char* ws = (char*)d_ws;
    size_t off = 0;
    auto alloc = [&](size_t elems) -> char* {
        char* p = ws + off;
        off += ((elems * 4 + 15) & ~(size_t)15);
        return p;
    };
    int*   cnt        = (int*)  alloc(N);                    // zeroed (deg)
    float* agg        = (float*)alloc((size_t)N * N_OUTC);   // zeroed
    size_t zero_bytes = off;
    int*   rowptr     = (int*)  alloc(N + 1);
    int*   bsum       = (int*)  alloc(nbl);
    float* dinv       = (float*)alloc(N);
    int*   loc        = (int*)  alloc(E);
    int*   eid_at_slot= (int*)  alloc(E);
    int*   col_sorted = (int*)  alloc(E);
    unsigned short* hws1 = (unsigned short*)alloc((size_t)N * G_DIM / 2);
    unsigned short* hws2 = (unsigned short*)alloc((size_t)N * G_DIM / 2);
    unsigned short* x3   = (unsigned short*)alloc((size_t)N * G_DIM / 2);
    (void)ws_size;

    hipMemsetAsync(d_ws, 0, zero_bytes, stream);

    loc_kernel<<<ebl, 256, 0, stream>>>(ei, E, cnt, loc);
    scanA_kernel<<<nbl, 256, 0, stream>>>(cnt, N, bsum);
    scanC_kernel<<<nbl, 256, 0, stream>>>(cnt, N, bsum, nbl, E, rowptr, dinv);
    build_kernel<<<ebl, 256, 0, stream>>>(ei, E, rowptr, loc, eid_at_slot, col_sorted);
    ecc_mfma_kernel<<<ebl, 256, 0, stream>>>(e, x, eid_at_slot, col_sorted,
                                             rowptr, N, E,
                                             w1, b1, w2, b2, w3, b3, agg);
    node1_kernel<<<nbl, 256, 0, stream>>>(agg, x, dinv, N, root, eb, g1w, hws1);
    gcn_gather_kernel<true><<<(N + 63) / 64, 256, 0, stream>>>(
        hws1, rowptr, col_sorted, dinv, N, g1b, g2w, hws2);
    gcn_gather_kernel<false><<<(N + 63) / 64, 256, 0, stream>>>(
        hws2, rowptr, col_sorted, dinv, N, g2b, nullptr, x3);
    pool_head_kernel<<<NGRAPH, 256, 0, stream>>>(x3, seg, N, d1w, d1b, d2w, d2b, out);
}

// Round 10
// 277.115 us; speedup vs baseline: 1.0984x; 1.0984x over previous
//
#include <hip/hip_runtime.h>

// Model dims (fixed by the reference)
#define S_DIM   6
#define H_DIM   20
#define F_INN   8
#define N_OUTC  20
#define G_DIM   32
#define D1_DIM  16
#define NGRAPH  512

typedef short short8 __attribute__((ext_vector_type(8)));
typedef float floatx4 __attribute__((ext_vector_type(4)));

__device__ __forceinline__ unsigned short f2bf(float f) {
    unsigned u = __float_as_uint(f);
    return (unsigned short)((u + 0x8000u) >> 16);   // RTN (ties up)
}
__device__ __forceinline__ float bf2f(unsigned short s) {
    return __uint_as_float(((unsigned)s) << 16);
}

// ---------------------------------------------------------------------------
// 1) loc: per-edge local slot within its row (1 int atomic/edge). cnt -> deg.
// ---------------------------------------------------------------------------
__global__ __launch_bounds__(256) void loc_kernel(
    const int* __restrict__ ei, int E, int* __restrict__ cnt,
    int* __restrict__ loc)
{
    int i = blockIdx.x * 256 + threadIdx.x;
    if (i >= E) return;
    loc[i] = atomicAdd(&cnt[ei[i]], 1);
}

// ---------------------------------------------------------------------------
// 2a) Per-block sums of deg (coalesced)
// ---------------------------------------------------------------------------
__global__ __launch_bounds__(256) void scanA_kernel(
    const int* __restrict__ deg, int N, int* __restrict__ bsum)
{
    int i = blockIdx.x * 256 + threadIdx.x;
    int v = (i < N) ? deg[i] : 0;
#pragma unroll
    for (int d = 1; d < 64; d <<= 1) v += __shfl_down(v, d, 64);
    __shared__ int ws[4];
    int wid = threadIdx.x >> 6;
    if ((threadIdx.x & 63) == 0) ws[wid] = v;
    __syncthreads();
    if (threadIdx.x == 0) bsum[blockIdx.x] = ws[0] + ws[1] + ws[2] + ws[3];
}

// ---------------------------------------------------------------------------
// 2b) Apply: block offset from bsum, block-local scan -> rowptr; dinv
// ---------------------------------------------------------------------------
__global__ __launch_bounds__(256) void scanC_kernel(
    const int* __restrict__ deg, int N, const int* __restrict__ bsum, int nbl,
    int E, int* __restrict__ rowptr, float* __restrict__ dinv)
{
    __shared__ int ws[4];
    __shared__ int sboff;
    int t = threadIdx.x;
    {
        int v = (t < nbl && t < blockIdx.x) ? bsum[t] : 0;
#pragma unroll
        for (int d = 1; d < 64; d <<= 1) v += __shfl_down(v, d, 64);
        int wid = t >> 6;
        if ((t & 63) == 0) ws[wid] = v;
        __syncthreads();
        if (t == 0) sboff = ws[0] + ws[1] + ws[2] + ws[3];
        __syncthreads();
    }

    int i = blockIdx.x * 256 + t;
    int d0 = (i < N) ? deg[i] : 0;
    int v = d0;
#pragma unroll
    for (int d = 1; d < 64; d <<= 1) {
        int u = __shfl_up(v, d, 64);
        if ((t & 63) >= d) v += u;
    }
    __shared__ int ws2[4];
    int wid = t >> 6;
    if ((t & 63) == 63) ws2[wid] = v;
    __syncthreads();
    int woff = 0;
    for (int w = 0; w < wid; ++w) woff += ws2[w];
    if (i < N) {
        rowptr[i] = sboff + woff + v - d0;
        dinv[i] = rsqrtf((float)d0 + 1.0f);
    }
    if (blockIdx.x == 0 && t == 0) rowptr[N] = E;
}

// ---------------------------------------------------------------------------
// 3) Build slot-ordered edge records: e_sorted[p] = {col, e[6], pad} (32 B,
//    ONE aligned scattered store per edge). Coalesced e reads. No atomics.
// ---------------------------------------------------------------------------
__global__ __launch_bounds__(256) void build_kernel(
    const int* __restrict__ ei, int E, const float* __restrict__ e,
    const int* __restrict__ rowptr, const int* __restrict__ loc,
    float* __restrict__ e_sorted)
{
    int i = blockIdx.x * 256 + threadIdx.x;
    if (i >= E) return;
    int r = ei[i];
    int c = ei[E + i];
    int p = rowptr[r] + loc[i];

    const float2* ep = (const float2*)&e[(size_t)i * S_DIM];   // 8B-aligned
    float2 e0 = ep[0], e1 = ep[1], e2 = ep[2];

    float4 r0, r1;
    r0.x = __int_as_float(c);
    r0.y = e0.x; r0.z = e0.y; r0.w = e1.x;
    r1.x = e1.y; r1.y = e2.x; r1.z = e2.y; r1.w = 0.0f;

    float4* dst = (float4*)&e_sorted[(size_t)p * 8];
    dst[0] = r0;
    dst[1] = r1;
}

// ---------------------------------------------------------------------------
// 4) ECC with MFMA einsum + segmented row reduction (CSR order).
//    Edge data arrives fully COALESCED via e_sorted. Emits col_sorted
//    (coalesced) for the GCN gathers. Round-8 structure (h2 on VALU).
// ---------------------------------------------------------------------------
__global__ __launch_bounds__(256) void ecc_mfma_kernel(
    const float* __restrict__ e_sorted, const float* __restrict__ x,
    const int* __restrict__ rowptr, int N, int E,
    const float* __restrict__ w1, const float* __restrict__ b1,
    const float* __restrict__ w2, const float* __restrict__ b2,
    const float* __restrict__ w3, const float* __restrict__ b3,
    float* __restrict__ agg, int* __restrict__ col_sorted)
{
    // Layout: [0,12288) B bf16[6144] ; [12288,22528) h2b[256][20] ;
    //         [22528,26624) xb[256][8].  lmsg float[256][20] (20480 B)
    //         aliases [0,20480) after the MFMA phase.
    __shared__ char smem[26624];
    __shared__ int rbounds[2];
    unsigned short* Bl = (unsigned short*)smem;
    unsigned short (*h2b)[N_OUTC] = (unsigned short (*)[N_OUTC])(smem + 12288);
    unsigned short (*xb)[F_INN]   = (unsigned short (*)[F_INN])(smem + 22528);
    float* lmsg = (float*)smem;

    int t = threadIdx.x;
    int j0 = blockIdx.x * 256;
    int jend = min(j0 + 256, E);
    int j = j0 + t;

    if (t < 2) {
        int s = (t == 0) ? j0 : (jend - 1);
        int lo = 0, hi = N - 1;
        while (lo < hi) {
            int m = (lo + hi + 1) >> 1;
            if (rowptr[m] <= s) lo = m; else hi = m - 1;
        }
        rbounds[t] = lo;
    }

    // ---- stage B into LDS, fragment-ready: [s][nt][quad][n][j] (bf16) ----
    for (int idx = t; idx < 6144; idx += 256) {
        int jj   = idx & 7;
        int n    = (idx >> 3) & 15;
        int quad = (idx >> 7) & 3;
        int nt   = (idx >> 9) & 1;
        int s    = idx >> 10;
        int K = 32 * s + quad * 8 + jj;
        int o = n + 16 * nt;
        float v = 0.0f;
        if (o < N_OUTC) {
            if (K < 160)      v = w3[(K >> 3) * 160 + (K & 7) * N_OUTC + o];
            else if (K < 168) v = b3[(K - 160) * N_OUTC + o];
        }
        Bl[idx] = f2bf(v);
    }

    // ---- per-edge MLP (fp32), coalesced edge record load ----
    if (j < E) {
        const float4* er = (const float4*)&e_sorted[(size_t)j * 8];
        float4 r0 = er[0], r1 = er[1];
        int c = __float_as_int(r0.x);
        col_sorted[j] = c;
        float ef[S_DIM] = {r0.y, r0.z, r0.w, r1.x, r1.y, r1.z};

        float h1[H_DIM];
#pragma unroll
        for (int jj = 0; jj < H_DIM; ++jj) {
            float a = b1[jj];
#pragma unroll
            for (int s = 0; s < S_DIM; ++s) a = fmaf(ef[s], w1[s * H_DIM + jj], a);
            h1[jj] = fmaxf(a, 0.0f);
        }

        float h2[H_DIM];
#pragma unroll
        for (int jj = 0; jj < H_DIM; ++jj) {
            float a = b2[jj];
#pragma unroll
            for (int k = 0; k < H_DIM; ++k) a = fmaf(h1[k], w2[k * H_DIM + jj], a);
            h2[jj] = fmaxf(a, 0.0f);
        }

        const float4* xp = (const float4*)&x[(size_t)c * F_INN];
        float4 xa = xp[0], xb4 = xp[1];
        float xf[F_INN] = {xa.x, xa.y, xa.z, xa.w, xb4.x, xb4.y, xb4.z, xb4.w};

#pragma unroll
        for (int o = 0; o < N_OUTC; ++o) h2b[t][o] = f2bf(h2[o]);
#pragma unroll
        for (int f = 0; f < F_INN; ++f) xb[t][f] = f2bf(xf[f]);
    } else {
#pragma unroll
        for (int o = 0; o < N_OUTC; ++o) h2b[t][o] = 0;
#pragma unroll
        for (int f = 0; f < F_INN; ++f) xb[t][f] = 0;
    }
    __syncthreads();

    // ---- load B fragments to registers ----
    int lane = t & 63;
    int quad = lane >> 4;
    int n = lane & 15;
    short8 Bf[12];
#pragma unroll
    for (int s = 0; s < 6; ++s)
#pragma unroll
        for (int nt = 0; nt < 2; ++nt)
            Bf[s * 2 + nt] = *(const short8*)&Bl[((((s * 2 + nt) * 4 + quad) * 16 + n) * 8)];

    // ---- MFMA: 4 m-tiles per wave, accs in registers ----
    int w = t >> 6;
    floatx4 acc0s[4], acc1s[4];
#pragma unroll
    for (int T = 0; T < 4; ++T) {
        int base = w * 64 + T * 16;
        int m = base + n;

        const short8 xv8 = *(const short8*)&xb[m][0];
        float xfl[F_INN];
#pragma unroll
        for (int jj = 0; jj < F_INN; ++jj) xfl[jj] = bf2f((unsigned short)xv8[jj]);

        floatx4 acc0 = {0.f, 0.f, 0.f, 0.f};
        floatx4 acc1 = {0.f, 0.f, 0.f, 0.f};
#pragma unroll
        for (int s = 0; s < 6; ++s) {
            short8 A = {0, 0, 0, 0, 0, 0, 0, 0};
            if (s < 5) {
                float h = bf2f(h2b[m][4 * s + quad]);
#pragma unroll
                for (int jj = 0; jj < F_INN; ++jj)
                    A[jj] = (short)f2bf(h * xfl[jj]);
            } else if (quad == 0) {
                A = xv8;                        // b3 rows: p = x
            }
            acc0 = __builtin_amdgcn_mfma_f32_16x16x32_bf16(A, Bf[s * 2 + 0], acc0, 0, 0, 0);
            acc1 = __builtin_amdgcn_mfma_f32_16x16x32_bf16(A, Bf[s * 2 + 1], acc1, 0, 0, 0);
        }
        acc0s[T] = acc0;
        acc1s[T] = acc1;
    }
    __syncthreads();   // all LDS reads done -> lmsg may overwrite everything

    // ---- C-write: col = n (+16 for acc1), row = base + quad*4 + r ----
#pragma unroll
    for (int T = 0; T < 4; ++T) {
        int base = w * 64 + T * 16;
#pragma unroll
        for (int r = 0; r < 4; ++r) {
            int row = base + quad * 4 + r;
            lmsg[row * N_OUTC + n] = acc0s[T][r];
            if (n < 4) lmsg[row * N_OUTC + 16 + n] = acc1s[T][r];
        }
    }
    __syncthreads();

    // ---- segmented row reduction into agg ----
    int r0 = rbounds[0], r1 = rbounds[1];
    int work = (r1 - r0 + 1) * 5;
    for (int ww = t; ww < work; ww += 256) {
        int row = r0 + ww / 5;
        int q = ww - (ww / 5) * 5;
        int a0 = rowptr[row], a1 = rowptr[row + 1];
        int s0 = max(a0, j0), s1 = min(a1, jend);
        float4 acc = make_float4(0.f, 0.f, 0.f, 0.f);
        for (int s = s0; s < s1; ++s) {
            const float4 v = *(const float4*)&lmsg[(s - j0) * N_OUTC + q * 4];
            acc.x += v.x; acc.y += v.y; acc.z += v.z; acc.w += v.w;
        }
        float* dst = &agg[(size_t)row * N_OUTC + q * 4];
        if (a0 >= j0 && a1 <= jend) {
            *(float4*)dst = acc;
        } else {
            unsafeAtomicAdd(dst + 0, acc.x);
            unsafeAtomicAdd(dst + 1, acc.y);
            unsafeAtomicAdd(dst + 2, acc.z);
            unsafeAtomicAdd(dst + 3, acc.w);
        }
    }
}

// ---------------------------------------------------------------------------
// 5) Node transform: x1 = relu(agg + x@root + b);
//    hws1 = bf16( dinv * (x1 @ gcn1_w) )
// ---------------------------------------------------------------------------
__global__ __launch_bounds__(256) void node1_kernel(
    const float* __restrict__ agg, const float* __restrict__ x,
    const float* __restrict__ dinv, int N,
    const float* __restrict__ root, const float* __restrict__ eb,
    const float* __restrict__ g1w,
    unsigned short* __restrict__ hws1)
{
    int n = blockIdx.x * 256 + threadIdx.x;
    if (n >= N) return;

    const float4* xp = (const float4*)&x[(size_t)n * F_INN];
    float4 xa = xp[0], xb = xp[1];
    float xf[F_INN] = {xa.x, xa.y, xa.z, xa.w, xb.x, xb.y, xb.z, xb.w};

    float x1[N_OUTC];
#pragma unroll
    for (int o = 0; o < N_OUTC; ++o) {
        float a = agg[(size_t)n * N_OUTC + o] + eb[o];
#pragma unroll
        for (int f = 0; f < F_INN; ++f) a = fmaf(xf[f], root[f * N_OUTC + o], a);
        x1[o] = fmaxf(a, 0.0f);
    }

    float di = dinv[n];
#pragma unroll
    for (int q = 0; q < 4; ++q) {
        short8 o8;
#pragma unroll
        for (int u = 0; u < 8; ++u) {
            int g = q * 8 + u;
            float a = 0.0f;
#pragma unroll
            for (int o = 0; o < N_OUTC; ++o) a = fmaf(x1[o], g1w[o * G_DIM + g], a);
            o8[u] = (short)f2bf(a * di);
        }
        *(short8*)&hws1[(size_t)n * G_DIM + q * 8] = o8;
    }
}

// ---------------------------------------------------------------------------
// 6) GCN gather on pre-scaled bf16 features. Thread = (node, chunk of 4);
//    each thread handles 8 channels (one 16B bf16 load per neighbor).
// ---------------------------------------------------------------------------
template<bool DO_MATMUL>
__global__ __launch_bounds__(256) void gcn_gather_kernel(
    const unsigned short* __restrict__ hws, const int* __restrict__ rowptr,
    const int* __restrict__ col_sorted, const float* __restrict__ dinv, int N,
    const float* __restrict__ bias, const float* __restrict__ w2,
    unsigned short* __restrict__ outbuf)
{
    __shared__ float x2s[64][33];
    __shared__ float w2s[G_DIM * G_DIM];

    int t = threadIdx.x;
    int nl = t >> 2;
    int q = t & 3;
    int n = blockIdx.x * 64 + nl;

    if (DO_MATMUL) {
        ((float4*)w2s)[t] = ((const float4*)w2)[t];
    }

    float xo[8];
    float di = 0.0f;
    if (n < N) {
        di = dinv[n];
        int j0 = rowptr[n], j1 = rowptr[n + 1];
        short8 sv = *(const short8*)&hws[(size_t)n * G_DIM + q * 8];
        float s[8];
#pragma unroll
        for (int k = 0; k < 8; ++k) s[k] = bf2f((unsigned short)sv[k]);
        for (int j = j0; j < j1; ++j) {
            int c = col_sorted[j];
            short8 v = *(const short8*)&hws[(size_t)c * G_DIM + q * 8];
#pragma unroll
            for (int k = 0; k < 8; ++k) s[k] += bf2f((unsigned short)v[k]);
        }
#pragma unroll
        for (int k = 0; k < 8; ++k)
            xo[k] = fmaxf(fmaf(di, s[k], bias[q * 8 + k]), 0.0f);
    } else {
#pragma unroll
        for (int k = 0; k < 8; ++k) xo[k] = 0.0f;
    }

    if (DO_MATMUL) {
#pragma unroll
        for (int k = 0; k < 8; ++k) x2s[nl][q * 8 + k] = xo[k];
        __syncthreads();
        if (n < N) {
            float a[8];
#pragma unroll
            for (int k = 0; k < 8; ++k) a[k] = 0.0f;
#pragma unroll
            for (int g = 0; g < G_DIM; ++g) {
                float xv = x2s[nl][g];
#pragma unroll
                for (int k = 0; k < 8; ++k)
                    a[k] = fmaf(xv, w2s[g * G_DIM + q * 8 + k], a[k]);
            }
            short8 o8;
#pragma unroll
            for (int k = 0; k < 8; ++k) o8[k] = (short)f2bf(a[k] * di);
            *(short8*)&outbuf[(size_t)n * G_DIM + q * 8] = o8;
        }
    } else {
        if (n < N) {
            short8 o8;
#pragma unroll
            for (int k = 0; k < 8; ++k) o8[k] = (short)f2bf(xo[k]);
            *(short8*)&outbuf[(size_t)n * G_DIM + q * 8] = o8;
        }
    }
}

// ---------------------------------------------------------------------------
// 7) Pool + head fused (x3 is bf16)
// ---------------------------------------------------------------------------
__global__ __launch_bounds__(256) void pool_head_kernel(
    const unsigned short* __restrict__ x3, const int* __restrict__ seg, int N,
    const float* __restrict__ d1w, const float* __restrict__ d1b,
    const float* __restrict__ d2w, const float* __restrict__ d2b,
    float* __restrict__ out)
{
    __shared__ float red[8][G_DIM];
    __shared__ float pvec[G_DIM];
    __shared__ int bounds[2];
    int g = blockIdx.x;
    int t = threadIdx.x;
    if (t < 2) {
        int target = g + t;
        int lo = 0, hi = N;
        while (lo < hi) {
            int m = (lo + hi) >> 1;
            if (seg[m] < target) lo = m + 1; else hi = m;
        }
        bounds[t] = lo;
    }
    __syncthreads();
    int n0 = bounds[0], n1 = bounds[1];
    int ch = t & (G_DIM - 1);
    int slice = t >> 5;
    float a = 0.0f;
    for (int n = n0 + slice; n < n1; n += 8)
        a += bf2f(x3[(size_t)n * G_DIM + ch]);
    red[slice][ch] = a;
    __syncthreads();
    if (slice == 0) {
        float s = red[0][ch];
#pragma unroll
        for (int k = 1; k < 8; ++k) s += red[k][ch];
        pvec[ch] = s;
    }
    __syncthreads();
    if (t < 64) {
        float acc = 0.0f;
        if (t < D1_DIM) {
            float tj = d1b[t];
#pragma unroll
            for (int gg = 0; gg < G_DIM; ++gg)
                tj = fmaf(pvec[gg], d1w[gg * D1_DIM + t], tj);
            acc = tj * d2w[t];
        }
#pragma unroll
        for (int d = 1; d < D1_DIM; d <<= 1) acc += __shfl_down(acc, d, 64);
        if (t == 0) out[g] = acc + d2b[0];
    }
}

// ---------------------------------------------------------------------------
extern "C" void kernel_launch(void* const* d_in, const int* in_sizes, int n_in,
                              void* d_out, int out_size, void* d_ws, size_t ws_size,
                              hipStream_t stream)
{
    const float* x    = (const float*)d_in[0];
    const float* e    = (const float*)d_in[1];
    const int*   ei   = (const int*)d_in[2];
    const int*   seg  = (const int*)d_in[3];
    const float* w1   = (const float*)d_in[4];
    const float* b1   = (const float*)d_in[5];
    const float* w2   = (const float*)d_in[6];
    const float* b2   = (const float*)d_in[7];
    const float* w3   = (const float*)d_in[8];
    const float* b3   = (const float*)d_in[9];
    const float* root = (const float*)d_in[10];
    const float* eb   = (const float*)d_in[11];
    const float* g1w  = (const float*)d_in[12];
    const float* g1b  = (const float*)d_in[13];
    const float* g2w  = (const float*)d_in[14];
    const float* g2b  = (const float*)d_in[15];
    const float* d1w  = (const float*)d_in[16];
    const float* d1b  = (const float*)d_in[17];
    const float* d2w  = (const float*)d_in[18];
    const float* d2b  = (const float*)d_in[19];

    const int N = in_sizes[3];            // 50000
    const int E = in_sizes[1] / S_DIM;    // 800000
    float* out = (float*)d_out;

    const int nbl = (N + 255) / 256;      // 196 (<= 256 for scanC)
    const int ebl = (E + 255) / 256;

    char* ws = (char*)d_ws;
    size_t off = 0;
    auto alloc = [&](size_t elems) -> char* {
        char* p = ws + off;
        off += ((elems * 4 + 15) & ~(size_t)15);
        return p;
    };
    int*   cnt        = (int*)  alloc(N);                    // zeroed (deg)
    float* agg        = (float*)alloc((size_t)N * N_OUTC);   // zeroed
    size_t zero_bytes = off;
    int*   rowptr     = (int*)  alloc(N + 1);
    int*   bsum       = (int*)  alloc(nbl);
    float* dinv       = (float*)alloc(N);
    int*   loc        = (int*)  alloc(E);
    int*   col_sorted = (int*)  alloc(E);
    float* e_sorted   = (float*)alloc((size_t)E * 8);        // {col,e[6],pad}
    unsigned short* hws1 = (unsigned short*)alloc((size_t)N * G_DIM / 2);
    unsigned short* hws2 = (unsigned short*)alloc((size_t)N * G_DIM / 2);
    unsigned short* x3   = (unsigned short*)alloc((size_t)N * G_DIM / 2);
    (void)ws_size;

    hipMemsetAsync(d_ws, 0, zero_bytes, stream);

    loc_kernel<<<ebl, 256, 0, stream>>>(ei, E, cnt, loc);
    scanA_kernel<<<nbl, 256, 0, stream>>>(cnt, N, bsum);
    scanC_kernel<<<nbl, 256, 0, stream>>>(cnt, N, bsum, nbl, E, rowptr, dinv);
    build_kernel<<<ebl, 256, 0, stream>>>(ei, E, e, rowptr, loc, e_sorted);
    ecc_mfma_kernel<<<ebl, 256, 0, stream>>>(e_sorted, x, rowptr, N, E,
                                             w1, b1, w2, b2, w3, b3,
                                             agg, col_sorted);
    node1_kernel<<<nbl, 256, 0, stream>>>(agg, x, dinv, N, root, eb, g1w, hws1);
    gcn_gather_kernel<true><<<(N + 63) / 64, 256, 0, stream>>>(
        hws1, rowptr, col_sorted, dinv, N, g1b, g2w, hws2);
    gcn_gather_kernel<false><<<(N + 63) / 64, 256, 0, stream>>>(
        hws2, rowptr, col_sorted, dinv, N, g2b, nullptr, x3);
    pool_head_kernel<<<NGRAPH, 256, 0, stream>>>(x3, seg, N, d1w, d1b, d2w, d2b, out);
}

// Round 11
// 269.741 us; speedup vs baseline: 1.1284x; 1.0273x over previous
//
#include <hip/hip_runtime.h>

// Model dims (fixed by the reference)
#define S_DIM   6
#define H_DIM   20
#define F_INN   8
#define N_OUTC  20
#define G_DIM   32
#define D1_DIM  16
#define NGRAPH  512

typedef short short8 __attribute__((ext_vector_type(8)));
typedef float floatx4 __attribute__((ext_vector_type(4)));

__device__ __forceinline__ unsigned short f2bf(float f) {
    unsigned u = __float_as_uint(f);
    return (unsigned short)((u + 0x8000u) >> 16);   // RTN (ties up)
}
__device__ __forceinline__ float bf2f(unsigned short s) {
    return __uint_as_float(((unsigned)s) << 16);
}

// ---------------------------------------------------------------------------
// 0) One-time prep: fragment-ready B3f table (6144 bf16 = 12.3 KB).
//    B[K][o], K = 32s+quad*8+j, o = n+16nt:
//      K<160: w3[(K>>3)*160+(K&7)*20+o] ; 160<=K<168: b3[(K-160)*20+o]
// ---------------------------------------------------------------------------
__global__ __launch_bounds__(256) void prep_kernel(
    const float* __restrict__ w3, const float* __restrict__ b3,
    unsigned short* __restrict__ B3f)
{
    int idx = blockIdx.x * 256 + threadIdx.x;
    if (idx >= 6144) return;
    int jj   = idx & 7;
    int n    = (idx >> 3) & 15;
    int quad = (idx >> 7) & 3;
    int nt   = (idx >> 9) & 1;
    int s    = idx >> 10;
    int K = 32 * s + quad * 8 + jj;
    int o = n + 16 * nt;
    float v = 0.0f;
    if (o < N_OUTC) {
        if (K < 160)      v = w3[(K >> 3) * 160 + (K & 7) * N_OUTC + o];
        else if (K < 168) v = b3[(K - 160) * N_OUTC + o];
    }
    B3f[idx] = f2bf(v);
}

// ---------------------------------------------------------------------------
// 1) loc: per-edge local slot within its row (1 int atomic/edge). cnt -> deg.
// ---------------------------------------------------------------------------
__global__ __launch_bounds__(256) void loc_kernel(
    const int* __restrict__ ei, int E, int* __restrict__ cnt,
    int* __restrict__ loc)
{
    int i = blockIdx.x * 256 + threadIdx.x;
    if (i >= E) return;
    loc[i] = atomicAdd(&cnt[ei[i]], 1);
}

// ---------------------------------------------------------------------------
// 2a) Per-block sums of deg (coalesced)
// ---------------------------------------------------------------------------
__global__ __launch_bounds__(256) void scanA_kernel(
    const int* __restrict__ deg, int N, int* __restrict__ bsum)
{
    int i = blockIdx.x * 256 + threadIdx.x;
    int v = (i < N) ? deg[i] : 0;
#pragma unroll
    for (int d = 1; d < 64; d <<= 1) v += __shfl_down(v, d, 64);
    __shared__ int ws[4];
    int wid = threadIdx.x >> 6;
    if ((threadIdx.x & 63) == 0) ws[wid] = v;
    __syncthreads();
    if (threadIdx.x == 0) bsum[blockIdx.x] = ws[0] + ws[1] + ws[2] + ws[3];
}

// ---------------------------------------------------------------------------
// 2b) Apply: block offset from bsum, block-local scan -> rowptr; dinv
// ---------------------------------------------------------------------------
__global__ __launch_bounds__(256) void scanC_kernel(
    const int* __restrict__ deg, int N, const int* __restrict__ bsum, int nbl,
    int E, int* __restrict__ rowptr, float* __restrict__ dinv)
{
    __shared__ int ws[4];
    __shared__ int sboff;
    int t = threadIdx.x;
    {
        int v = (t < nbl && t < blockIdx.x) ? bsum[t] : 0;
#pragma unroll
        for (int d = 1; d < 64; d <<= 1) v += __shfl_down(v, d, 64);
        int wid = t >> 6;
        if ((t & 63) == 0) ws[wid] = v;
        __syncthreads();
        if (t == 0) sboff = ws[0] + ws[1] + ws[2] + ws[3];
        __syncthreads();
    }

    int i = blockIdx.x * 256 + t;
    int d0 = (i < N) ? deg[i] : 0;
    int v = d0;
#pragma unroll
    for (int d = 1; d < 64; d <<= 1) {
        int u = __shfl_up(v, d, 64);
        if ((t & 63) >= d) v += u;
    }
    __shared__ int ws2[4];
    int wid = t >> 6;
    if ((t & 63) == 63) ws2[wid] = v;
    __syncthreads();
    int woff = 0;
    for (int w = 0; w < wid; ++w) woff += ws2[w];
    if (i < N) {
        rowptr[i] = sboff + woff + v - d0;
        dinv[i] = rsqrtf((float)d0 + 1.0f);
    }
    if (blockIdx.x == 0 && t == 0) rowptr[N] = E;
}

// ---------------------------------------------------------------------------
// 3) Build slot-ordered edge records: e_sorted[p] = {col:int, e[6]:bf16}
//    = exactly 16 B, ONE aligned scattered store per edge. No atomics.
// ---------------------------------------------------------------------------
__global__ __launch_bounds__(256) void build_kernel(
    const int* __restrict__ ei, int E, const float* __restrict__ e,
    const int* __restrict__ rowptr, const int* __restrict__ loc,
    int4* __restrict__ e_sorted)
{
    int i = blockIdx.x * 256 + threadIdx.x;
    if (i >= E) return;
    int r = ei[i];
    int c = ei[E + i];
    int p = rowptr[r] + loc[i];

    const float2* ep = (const float2*)&e[(size_t)i * S_DIM];   // 8B-aligned
    float2 e0 = ep[0], e1 = ep[1], e2 = ep[2];

    int4 rec;
    rec.x = c;
    rec.y = (int)f2bf(e0.x) | ((int)f2bf(e0.y) << 16);
    rec.z = (int)f2bf(e1.x) | ((int)f2bf(e1.y) << 16);
    rec.w = (int)f2bf(e2.x) | ((int)f2bf(e2.y) << 16);
    e_sorted[p] = rec;
}

// ---------------------------------------------------------------------------
// 4) ECC with MFMA einsum + segmented row reduction (CSR order).
//    B fragments from precomputed global table (L1-resident) — no B staging.
//    LDS: union{ h2b[256][20]+xb[256][8] (14.3K) , lmsg[256][20] (20.5K) }.
// ---------------------------------------------------------------------------
__global__ __launch_bounds__(256) void ecc_mfma_kernel(
    const int4* __restrict__ e_sorted, const float* __restrict__ x,
    const int* __restrict__ rowptr, int N, int E,
    const unsigned short* __restrict__ B3f,
    const float* __restrict__ w1, const float* __restrict__ b1,
    const float* __restrict__ w2, const float* __restrict__ b2,
    float* __restrict__ agg, int* __restrict__ col_sorted)
{
    __shared__ char smem[20480];
    __shared__ int rbounds[2];
    unsigned short (*h2b)[N_OUTC] = (unsigned short (*)[N_OUTC])smem;          // 10240
    unsigned short (*xb)[F_INN]   = (unsigned short (*)[F_INN])(smem + 10240); // 4096
    float* lmsg = (float*)smem;                                                // 20480

    int t = threadIdx.x;
    int j0 = blockIdx.x * 256;
    int jend = min(j0 + 256, E);
    int j = j0 + t;

    if (t < 2) {
        int s = (t == 0) ? j0 : (jend - 1);
        int lo = 0, hi = N - 1;
        while (lo < hi) {
            int m = (lo + hi + 1) >> 1;
            if (rowptr[m] <= s) lo = m; else hi = m - 1;
        }
        rbounds[t] = lo;
    }

    // ---- per-edge MLP (fp32), 16B coalesced edge record load ----
    if (j < E) {
        int4 rec = e_sorted[j];
        int c = rec.x;
        col_sorted[j] = c;
        float ef[S_DIM] = {
            bf2f((unsigned short)(rec.y & 0xffff)),
            bf2f((unsigned short)((unsigned)rec.y >> 16)),
            bf2f((unsigned short)(rec.z & 0xffff)),
            bf2f((unsigned short)((unsigned)rec.z >> 16)),
            bf2f((unsigned short)(rec.w & 0xffff)),
            bf2f((unsigned short)((unsigned)rec.w >> 16))
        };

        float h1[H_DIM];
#pragma unroll
        for (int jj = 0; jj < H_DIM; ++jj) {
            float a = b1[jj];
#pragma unroll
            for (int s = 0; s < S_DIM; ++s) a = fmaf(ef[s], w1[s * H_DIM + jj], a);
            h1[jj] = fmaxf(a, 0.0f);
        }

        float h2[H_DIM];
#pragma unroll
        for (int jj = 0; jj < H_DIM; ++jj) {
            float a = b2[jj];
#pragma unroll
            for (int k = 0; k < H_DIM; ++k) a = fmaf(h1[k], w2[k * H_DIM + jj], a);
            h2[jj] = fmaxf(a, 0.0f);
        }

        const float4* xp = (const float4*)&x[(size_t)c * F_INN];
        float4 xa = xp[0], xb4 = xp[1];
        float xf[F_INN] = {xa.x, xa.y, xa.z, xa.w, xb4.x, xb4.y, xb4.z, xb4.w};

#pragma unroll
        for (int o = 0; o < N_OUTC; ++o) h2b[t][o] = f2bf(h2[o]);
#pragma unroll
        for (int f = 0; f < F_INN; ++f) xb[t][f] = f2bf(xf[f]);
    } else {
#pragma unroll
        for (int o = 0; o < N_OUTC; ++o) h2b[t][o] = 0;
#pragma unroll
        for (int f = 0; f < F_INN; ++f) xb[t][f] = 0;
    }
    __syncthreads();

    // ---- B fragments straight from global (hot in L1 after block 0) ----
    int lane = t & 63;
    int quad = lane >> 4;
    int n = lane & 15;
    const short8* Bg = (const short8*)B3f;
    short8 Bf[12];
#pragma unroll
    for (int s = 0; s < 6; ++s)
#pragma unroll
        for (int nt = 0; nt < 2; ++nt)
            Bf[s * 2 + nt] = Bg[((s * 2 + nt) * 4 + quad) * 16 + n];

    // ---- MFMA: 4 m-tiles per wave, accs in registers (intra-wave reads) ----
    int w = t >> 6;
    floatx4 acc0s[4], acc1s[4];
#pragma unroll
    for (int T = 0; T < 4; ++T) {
        int base = w * 64 + T * 16;
        int m = base + n;

        const short8 xv8 = *(const short8*)&xb[m][0];
        float xfl[F_INN];
#pragma unroll
        for (int jj = 0; jj < F_INN; ++jj) xfl[jj] = bf2f((unsigned short)xv8[jj]);

        floatx4 acc0 = {0.f, 0.f, 0.f, 0.f};
        floatx4 acc1 = {0.f, 0.f, 0.f, 0.f};
#pragma unroll
        for (int s = 0; s < 6; ++s) {
            short8 A = {0, 0, 0, 0, 0, 0, 0, 0};
            if (s < 5) {
                float h = bf2f(h2b[m][4 * s + quad]);
#pragma unroll
                for (int jj = 0; jj < F_INN; ++jj)
                    A[jj] = (short)f2bf(h * xfl[jj]);
            } else if (quad == 0) {
                A = xv8;                        // b3 rows: p = x
            }
            acc0 = __builtin_amdgcn_mfma_f32_16x16x32_bf16(A, Bf[s * 2 + 0], acc0, 0, 0, 0);
            acc1 = __builtin_amdgcn_mfma_f32_16x16x32_bf16(A, Bf[s * 2 + 1], acc1, 0, 0, 0);
        }
        acc0s[T] = acc0;
        acc1s[T] = acc1;
    }
    __syncthreads();   // all staging reads done -> lmsg may alias everything

    // ---- C-write: col = n (+16 for acc1), row = base + quad*4 + r ----
#pragma unroll
    for (int T = 0; T < 4; ++T) {
        int base = w * 64 + T * 16;
#pragma unroll
        for (int r = 0; r < 4; ++r) {
            int row = base + quad * 4 + r;
            lmsg[row * N_OUTC + n] = acc0s[T][r];
            if (n < 4) lmsg[row * N_OUTC + 16 + n] = acc1s[T][r];
        }
    }
    __syncthreads();

    // ---- segmented row reduction into agg ----
    int r0 = rbounds[0], r1 = rbounds[1];
    int work = (r1 - r0 + 1) * 5;
    for (int ww = t; ww < work; ww += 256) {
        int row = r0 + ww / 5;
        int q = ww - (ww / 5) * 5;
        int a0 = rowptr[row], a1 = rowptr[row + 1];
        int s0 = max(a0, j0), s1 = min(a1, jend);
        float4 acc = make_float4(0.f, 0.f, 0.f, 0.f);
        for (int s = s0; s < s1; ++s) {
            const float4 v = *(const float4*)&lmsg[(s - j0) * N_OUTC + q * 4];
            acc.x += v.x; acc.y += v.y; acc.z += v.z; acc.w += v.w;
        }
        float* dst = &agg[(size_t)row * N_OUTC + q * 4];
        if (a0 >= j0 && a1 <= jend) {
            *(float4*)dst = acc;
        } else {
            unsafeAtomicAdd(dst + 0, acc.x);
            unsafeAtomicAdd(dst + 1, acc.y);
            unsafeAtomicAdd(dst + 2, acc.z);
            unsafeAtomicAdd(dst + 3, acc.w);
        }
    }
}

// ---------------------------------------------------------------------------
// 5) Node transform: x1 = relu(agg + x@root + b);
//    hws1 = bf16( dinv * (x1 @ gcn1_w) )
// ---------------------------------------------------------------------------
__global__ __launch_bounds__(256) void node1_kernel(
    const float* __restrict__ agg, const float* __restrict__ x,
    const float* __restrict__ dinv, int N,
    const float* __restrict__ root, const float* __restrict__ eb,
    const float* __restrict__ g1w,
    unsigned short* __restrict__ hws1)
{
    int n = blockIdx.x * 256 + threadIdx.x;
    if (n >= N) return;

    const float4* xp = (const float4*)&x[(size_t)n * F_INN];
    float4 xa = xp[0], xb = xp[1];
    float xf[F_INN] = {xa.x, xa.y, xa.z, xa.w, xb.x, xb.y, xb.z, xb.w};

    float x1[N_OUTC];
#pragma unroll
    for (int o = 0; o < N_OUTC; ++o) {
        float a = agg[(size_t)n * N_OUTC + o] + eb[o];
#pragma unroll
        for (int f = 0; f < F_INN; ++f) a = fmaf(xf[f], root[f * N_OUTC + o], a);
        x1[o] = fmaxf(a, 0.0f);
    }

    float di = dinv[n];
#pragma unroll
    for (int q = 0; q < 4; ++q) {
        short8 o8;
#pragma unroll
        for (int u = 0; u < 8; ++u) {
            int g = q * 8 + u;
            float a = 0.0f;
#pragma unroll
            for (int o = 0; o < N_OUTC; ++o) a = fmaf(x1[o], g1w[o * G_DIM + g], a);
            o8[u] = (short)f2bf(a * di);
        }
        *(short8*)&hws1[(size_t)n * G_DIM + q * 8] = o8;
    }
}

// ---------------------------------------------------------------------------
// 6) GCN gather on pre-scaled bf16 features. Thread = (node, chunk of 4);
//    each thread handles 8 channels (one 16B bf16 load per neighbor).
// ---------------------------------------------------------------------------
template<bool DO_MATMUL>
__global__ __launch_bounds__(256) void gcn_gather_kernel(
    const unsigned short* __restrict__ hws, const int* __restrict__ rowptr,
    const int* __restrict__ col_sorted, const float* __restrict__ dinv, int N,
    const float* __restrict__ bias, const float* __restrict__ w2,
    unsigned short* __restrict__ outbuf)
{
    __shared__ float x2s[64][33];
    __shared__ float w2s[G_DIM * G_DIM];

    int t = threadIdx.x;
    int nl = t >> 2;
    int q = t & 3;
    int n = blockIdx.x * 64 + nl;

    if (DO_MATMUL) {
        ((float4*)w2s)[t] = ((const float4*)w2)[t];
    }

    float xo[8];
    float di = 0.0f;
    if (n < N) {
        di = dinv[n];
        int j0 = rowptr[n], j1 = rowptr[n + 1];
        short8 sv = *(const short8*)&hws[(size_t)n * G_DIM + q * 8];
        float s[8];
#pragma unroll
        for (int k = 0; k < 8; ++k) s[k] = bf2f((unsigned short)sv[k]);
        for (int j = j0; j < j1; ++j) {
            int c = col_sorted[j];
            short8 v = *(const short8*)&hws[(size_t)c * G_DIM + q * 8];
#pragma unroll
            for (int k = 0; k < 8; ++k) s[k] += bf2f((unsigned short)v[k]);
        }
#pragma unroll
        for (int k = 0; k < 8; ++k)
            xo[k] = fmaxf(fmaf(di, s[k], bias[q * 8 + k]), 0.0f);
    } else {
#pragma unroll
        for (int k = 0; k < 8; ++k) xo[k] = 0.0f;
    }

    if (DO_MATMUL) {
#pragma unroll
        for (int k = 0; k < 8; ++k) x2s[nl][q * 8 + k] = xo[k];
        __syncthreads();
        if (n < N) {
            float a[8];
#pragma unroll
            for (int k = 0; k < 8; ++k) a[k] = 0.0f;
#pragma unroll
            for (int g = 0; g < G_DIM; ++g) {
                float xv = x2s[nl][g];
#pragma unroll
                for (int k = 0; k < 8; ++k)
                    a[k] = fmaf(xv, w2s[g * G_DIM + q * 8 + k], a[k]);
            }
            short8 o8;
#pragma unroll
            for (int k = 0; k < 8; ++k) o8[k] = (short)f2bf(a[k] * di);
            *(short8*)&outbuf[(size_t)n * G_DIM + q * 8] = o8;
        }
    } else {
        if (n < N) {
            short8 o8;
#pragma unroll
            for (int k = 0; k < 8; ++k) o8[k] = (short)f2bf(xo[k]);
            *(short8*)&outbuf[(size_t)n * G_DIM + q * 8] = o8;
        }
    }
}

// ---------------------------------------------------------------------------
// 7) Pool + head fused (x3 is bf16)
// ---------------------------------------------------------------------------
__global__ __launch_bounds__(256) void pool_head_kernel(
    const unsigned short* __restrict__ x3, const int* __restrict__ seg, int N,
    const float* __restrict__ d1w, const float* __restrict__ d1b,
    const float* __restrict__ d2w, const float* __restrict__ d2b,
    float* __restrict__ out)
{
    __shared__ float red[8][G_DIM];
    __shared__ float pvec[G_DIM];
    __shared__ int bounds[2];
    int g = blockIdx.x;
    int t = threadIdx.x;
    if (t < 2) {
        int target = g + t;
        int lo = 0, hi = N;
        while (lo < hi) {
            int m = (lo + hi) >> 1;
            if (seg[m] < target) lo = m + 1; else hi = m;
        }
        bounds[t] = lo;
    }
    __syncthreads();
    int n0 = bounds[0], n1 = bounds[1];
    int ch = t & (G_DIM - 1);
    int slice = t >> 5;
    float a = 0.0f;
    for (int n = n0 + slice; n < n1; n += 8)
        a += bf2f(x3[(size_t)n * G_DIM + ch]);
    red[slice][ch] = a;
    __syncthreads();
    if (slice == 0) {
        float s = red[0][ch];
#pragma unroll
        for (int k = 1; k < 8; ++k) s += red[k][ch];
        pvec[ch] = s;
    }
    __syncthreads();
    if (t < 64) {
        float acc = 0.0f;
        if (t < D1_DIM) {
            float tj = d1b[t];
#pragma unroll
            for (int gg = 0; gg < G_DIM; ++gg)
                tj = fmaf(pvec[gg], d1w[gg * D1_DIM + t], tj);
            acc = tj * d2w[t];
        }
#pragma unroll
        for (int d = 1; d < D1_DIM; d <<= 1) acc += __shfl_down(acc, d, 64);
        if (t == 0) out[g] = acc + d2b[0];
    }
}

// ---------------------------------------------------------------------------
extern "C" void kernel_launch(void* const* d_in, const int* in_sizes, int n_in,
                              void* d_out, int out_size, void* d_ws, size_t ws_size,
                              hipStream_t stream)
{
    const float* x    = (const float*)d_in[0];
    const float* e    = (const float*)d_in[1];
    const int*   ei   = (const int*)d_in[2];
    const int*   seg  = (const int*)d_in[3];
    const float* w1   = (const float*)d_in[4];
    const float* b1   = (const float*)d_in[5];
    const float* w2   = (const float*)d_in[6];
    const float* b2   = (const float*)d_in[7];
    const float* w3   = (const float*)d_in[8];
    const float* b3   = (const float*)d_in[9];
    const float* root = (const float*)d_in[10];
    const float* eb   = (const float*)d_in[11];
    const float* g1w  = (const float*)d_in[12];
    const float* g1b  = (const float*)d_in[13];
    const float* g2w  = (const float*)d_in[14];
    const float* g2b  = (const float*)d_in[15];
    const float* d1w  = (const float*)d_in[16];
    const float* d1b  = (const float*)d_in[17];
    const float* d2w  = (const float*)d_in[18];
    const float* d2b  = (const float*)d_in[19];

    const int N = in_sizes[3];            // 50000
    const int E = in_sizes[1] / S_DIM;    // 800000
    float* out = (float*)d_out;

    const int nbl = (N + 255) / 256;      // 196 (<= 256 for scanC)
    const int ebl = (E + 255) / 256;

    char* ws = (char*)d_ws;
    size_t off = 0;
    auto alloc = [&](size_t elems) -> char* {
        char* p = ws + off;
        off += ((elems * 4 + 15) & ~(size_t)15);
        return p;
    };
    int*   cnt        = (int*)  alloc(N);                    // zeroed (deg)
    float* agg        = (float*)alloc((size_t)N * N_OUTC);   // zeroed
    size_t zero_bytes = off;
    int*   rowptr     = (int*)  alloc(N + 1);
    int*   bsum       = (int*)  alloc(nbl);
    float* dinv       = (float*)alloc(N);
    int*   loc        = (int*)  alloc(E);
    int*   col_sorted = (int*)  alloc(E);
    unsigned short* B3f = (unsigned short*)alloc(6144 / 2);  // 12.3 KB
    int4*  e_sorted   = (int4*) alloc((size_t)E * 4);        // 16 B/edge
    unsigned short* hws1 = (unsigned short*)alloc((size_t)N * G_DIM / 2);
    unsigned short* hws2 = (unsigned short*)alloc((size_t)N * G_DIM / 2);
    unsigned short* x3   = (unsigned short*)alloc((size_t)N * G_DIM / 2);
    (void)ws_size;

    hipMemsetAsync(d_ws, 0, zero_bytes, stream);

    prep_kernel<<<24, 256, 0, stream>>>(w3, b3, B3f);
    loc_kernel<<<ebl, 256, 0, stream>>>(ei, E, cnt, loc);
    scanA_kernel<<<nbl, 256, 0, stream>>>(cnt, N, bsum);
    scanC_kernel<<<nbl, 256, 0, stream>>>(cnt, N, bsum, nbl, E, rowptr, dinv);
    build_kernel<<<ebl, 256, 0, stream>>>(ei, E, e, rowptr, loc, e_sorted);
    ecc_mfma_kernel<<<ebl, 256, 0, stream>>>(e_sorted, x, rowptr, N, E, B3f,
                                             w1, b1, w2, b2, agg, col_sorted);
    node1_kernel<<<nbl, 256, 0, stream>>>(agg, x, dinv, N, root, eb, g1w, hws1);
    gcn_gather_kernel<true><<<(N + 63) / 64, 256, 0, stream>>>(
        hws1, rowptr, col_sorted, dinv, N, g1b, g2w, hws2);
    gcn_gather_kernel<false><<<(N + 63) / 64, 256, 0, stream>>>(
        hws2, rowptr, col_sorted, dinv, N, g2b, nullptr, x3);
    pool_head_kernel<<<NGRAPH, 256, 0, stream>>>(x3, seg, N, d1w, d1b, d2w, d2b, out);
}

// Round 12
// 264.445 us; speedup vs baseline: 1.1510x; 1.0200x over previous
//
#include <hip/hip_runtime.h>

// Model dims (fixed by the reference)
#define S_DIM   6
#define H_DIM   20
#define F_INN   8
#define N_OUTC  20
#define G_DIM   32
#define D1_DIM  16
#define NGRAPH  512
#define CAP     32      // max fast-path rows per ECC block (LDS x1buf)

typedef short short8 __attribute__((ext_vector_type(8)));
typedef float floatx4 __attribute__((ext_vector_type(4)));

__device__ __forceinline__ unsigned short f2bf(float f) {
    unsigned u = __float_as_uint(f);
    return (unsigned short)((u + 0x8000u) >> 16);   // RTN (ties up)
}
__device__ __forceinline__ float bf2f(unsigned short s) {
    return __uint_as_float(((unsigned)s) << 16);
}

// ---------------------------------------------------------------------------
// 0) One-time prep: fragment-ready B3f table (6144 bf16 = 12.3 KB).
// ---------------------------------------------------------------------------
__global__ __launch_bounds__(256) void prep_kernel(
    const float* __restrict__ w3, const float* __restrict__ b3,
    unsigned short* __restrict__ B3f)
{
    int idx = blockIdx.x * 256 + threadIdx.x;
    if (idx >= 6144) return;
    int jj   = idx & 7;
    int n    = (idx >> 3) & 15;
    int quad = (idx >> 7) & 3;
    int nt   = (idx >> 9) & 1;
    int s    = idx >> 10;
    int K = 32 * s + quad * 8 + jj;
    int o = n + 16 * nt;
    float v = 0.0f;
    if (o < N_OUTC) {
        if (K < 160)      v = w3[(K >> 3) * 160 + (K & 7) * N_OUTC + o];
        else if (K < 168) v = b3[(K - 160) * N_OUTC + o];
    }
    B3f[idx] = f2bf(v);
}

// ---------------------------------------------------------------------------
// 1) loc: per-edge local slot within its row (1 int atomic/edge). cnt -> deg.
// ---------------------------------------------------------------------------
__global__ __launch_bounds__(256) void loc_kernel(
    const int* __restrict__ ei, int E, int* __restrict__ cnt,
    int* __restrict__ loc)
{
    int i = blockIdx.x * 256 + threadIdx.x;
    if (i >= E) return;
    loc[i] = atomicAdd(&cnt[ei[i]], 1);
}

// ---------------------------------------------------------------------------
// 2a) Per-block sums of deg (coalesced)
// ---------------------------------------------------------------------------
__global__ __launch_bounds__(256) void scanA_kernel(
    const int* __restrict__ deg, int N, int* __restrict__ bsum)
{
    int i = blockIdx.x * 256 + threadIdx.x;
    int v = (i < N) ? deg[i] : 0;
#pragma unroll
    for (int d = 1; d < 64; d <<= 1) v += __shfl_down(v, d, 64);
    __shared__ int ws[4];
    int wid = threadIdx.x >> 6;
    if ((threadIdx.x & 63) == 0) ws[wid] = v;
    __syncthreads();
    if (threadIdx.x == 0) bsum[blockIdx.x] = ws[0] + ws[1] + ws[2] + ws[3];
}

// ---------------------------------------------------------------------------
// 2b) Apply: block offset from bsum, block-local scan -> rowptr; dinv
// ---------------------------------------------------------------------------
__global__ __launch_bounds__(256) void scanC_kernel(
    const int* __restrict__ deg, int N, const int* __restrict__ bsum, int nbl,
    int E, int* __restrict__ rowptr, float* __restrict__ dinv)
{
    __shared__ int ws[4];
    __shared__ int sboff;
    int t = threadIdx.x;
    {
        int v = (t < nbl && t < blockIdx.x) ? bsum[t] : 0;
#pragma unroll
        for (int d = 1; d < 64; d <<= 1) v += __shfl_down(v, d, 64);
        int wid = t >> 6;
        if ((t & 63) == 0) ws[wid] = v;
        __syncthreads();
        if (t == 0) sboff = ws[0] + ws[1] + ws[2] + ws[3];
        __syncthreads();
    }

    int i = blockIdx.x * 256 + t;
    int d0 = (i < N) ? deg[i] : 0;
    int v = d0;
#pragma unroll
    for (int d = 1; d < 64; d <<= 1) {
        int u = __shfl_up(v, d, 64);
        if ((t & 63) >= d) v += u;
    }
    __shared__ int ws2[4];
    int wid = t >> 6;
    if ((t & 63) == 63) ws2[wid] = v;
    __syncthreads();
    int woff = 0;
    for (int w = 0; w < wid; ++w) woff += ws2[w];
    if (i < N) {
        rowptr[i] = sboff + woff + v - d0;
        dinv[i] = rsqrtf((float)d0 + 1.0f);
    }
    if (blockIdx.x == 0 && t == 0) rowptr[N] = E;
}

// ---------------------------------------------------------------------------
// 3) Build slot-ordered edge records: e_sorted[p] = {col:int, e[6]:bf16}
//    = exactly 16 B, ONE aligned scattered store per edge. No atomics.
// ---------------------------------------------------------------------------
__global__ __launch_bounds__(256) void build_kernel(
    const int* __restrict__ ei, int E, const float* __restrict__ e,
    const int* __restrict__ rowptr, const int* __restrict__ loc,
    int4* __restrict__ e_sorted)
{
    int i = blockIdx.x * 256 + threadIdx.x;
    if (i >= E) return;
    int r = ei[i];
    int c = ei[E + i];
    int p = rowptr[r] + loc[i];

    const float2* ep = (const float2*)&e[(size_t)i * S_DIM];   // 8B-aligned
    float2 e0 = ep[0], e1 = ep[1], e2 = ep[2];

    int4 rec;
    rec.x = c;
    rec.y = (int)f2bf(e0.x) | ((int)f2bf(e0.y) << 16);
    rec.z = (int)f2bf(e1.x) | ((int)f2bf(e1.y) << 16);
    rec.w = (int)f2bf(e2.x) | ((int)f2bf(e2.y) << 16);
    e_sorted[p] = rec;
}

// ---------------------------------------------------------------------------
// 4) ECC: MLP (fp32 VALU) -> MFMA einsum -> segmented reduce WITH FUSED
//    node1 transform for fully-owned rows (x1=relu(agg+x@root+eb);
//    hws1=bf16(dinv*(x1@g1w))). Boundary/overflow rows -> agg (+cleanup).
// ---------------------------------------------------------------------------
__global__ __launch_bounds__(256) void ecc_mfma_kernel(
    const int4* __restrict__ e_sorted, const float* __restrict__ x,
    const int* __restrict__ rowptr, int N, int E,
    const unsigned short* __restrict__ B3f,
    const float* __restrict__ w1, const float* __restrict__ b1,
    const float* __restrict__ w2, const float* __restrict__ b2,
    const float* __restrict__ root, const float* __restrict__ eb,
    const float* __restrict__ g1w,
    float* __restrict__ agg, int* __restrict__ col_sorted,
    unsigned short* __restrict__ hws1)
{
    __shared__ char smem[20480];
    __shared__ float x1buf[CAP * N_OUTC];   // 2.5 KB
    __shared__ int rbounds[2];
    unsigned short (*h2b)[N_OUTC] = (unsigned short (*)[N_OUTC])smem;          // 10240
    unsigned short (*xb)[F_INN]   = (unsigned short (*)[F_INN])(smem + 10240); // 4096
    float* lmsg = (float*)smem;                                                // 20480

    int t = threadIdx.x;
    int j0 = blockIdx.x * 256;
    int jend = min(j0 + 256, E);
    int j = j0 + t;

    if (t < 2) {
        int s = (t == 0) ? j0 : (jend - 1);
        int lo = 0, hi = N - 1;
        while (lo < hi) {
            int m = (lo + hi + 1) >> 1;
            if (rowptr[m] <= s) lo = m; else hi = m - 1;
        }
        rbounds[t] = lo;
    }

    // ---- per-edge MLP (fp32), 16B coalesced edge record load ----
    if (j < E) {
        int4 rec = e_sorted[j];
        int c = rec.x;
        col_sorted[j] = c;
        float ef[S_DIM] = {
            bf2f((unsigned short)(rec.y & 0xffff)),
            bf2f((unsigned short)((unsigned)rec.y >> 16)),
            bf2f((unsigned short)(rec.z & 0xffff)),
            bf2f((unsigned short)((unsigned)rec.z >> 16)),
            bf2f((unsigned short)(rec.w & 0xffff)),
            bf2f((unsigned short)((unsigned)rec.w >> 16))
        };

        float h1[H_DIM];
#pragma unroll
        for (int jj = 0; jj < H_DIM; ++jj) {
            float a = b1[jj];
#pragma unroll
            for (int s = 0; s < S_DIM; ++s) a = fmaf(ef[s], w1[s * H_DIM + jj], a);
            h1[jj] = fmaxf(a, 0.0f);
        }

        float h2[H_DIM];
#pragma unroll
        for (int jj = 0; jj < H_DIM; ++jj) {
            float a = b2[jj];
#pragma unroll
            for (int k = 0; k < H_DIM; ++k) a = fmaf(h1[k], w2[k * H_DIM + jj], a);
            h2[jj] = fmaxf(a, 0.0f);
        }

        const float4* xp = (const float4*)&x[(size_t)c * F_INN];
        float4 xa = xp[0], xb4 = xp[1];
        float xf[F_INN] = {xa.x, xa.y, xa.z, xa.w, xb4.x, xb4.y, xb4.z, xb4.w};

#pragma unroll
        for (int o = 0; o < N_OUTC; ++o) h2b[t][o] = f2bf(h2[o]);
#pragma unroll
        for (int f = 0; f < F_INN; ++f) xb[t][f] = f2bf(xf[f]);
    } else {
#pragma unroll
        for (int o = 0; o < N_OUTC; ++o) h2b[t][o] = 0;
#pragma unroll
        for (int f = 0; f < F_INN; ++f) xb[t][f] = 0;
    }
    __syncthreads();

    // ---- B fragments straight from global (hot in L1 after block 0) ----
    int lane = t & 63;
    int quad = lane >> 4;
    int n = lane & 15;
    const short8* Bg = (const short8*)B3f;
    short8 Bf[12];
#pragma unroll
    for (int s = 0; s < 6; ++s)
#pragma unroll
        for (int nt = 0; nt < 2; ++nt)
            Bf[s * 2 + nt] = Bg[((s * 2 + nt) * 4 + quad) * 16 + n];

    // ---- MFMA: 4 m-tiles per wave, accs in registers ----
    int w = t >> 6;
    floatx4 acc0s[4], acc1s[4];
#pragma unroll
    for (int T = 0; T < 4; ++T) {
        int base = w * 64 + T * 16;
        int m = base + n;

        const short8 xv8 = *(const short8*)&xb[m][0];
        float xfl[F_INN];
#pragma unroll
        for (int jj = 0; jj < F_INN; ++jj) xfl[jj] = bf2f((unsigned short)xv8[jj]);

        floatx4 acc0 = {0.f, 0.f, 0.f, 0.f};
        floatx4 acc1 = {0.f, 0.f, 0.f, 0.f};
#pragma unroll
        for (int s = 0; s < 6; ++s) {
            short8 A = {0, 0, 0, 0, 0, 0, 0, 0};
            if (s < 5) {
                float h = bf2f(h2b[m][4 * s + quad]);
#pragma unroll
                for (int jj = 0; jj < F_INN; ++jj)
                    A[jj] = (short)f2bf(h * xfl[jj]);
            } else if (quad == 0) {
                A = xv8;                        // b3 rows: p = x
            }
            acc0 = __builtin_amdgcn_mfma_f32_16x16x32_bf16(A, Bf[s * 2 + 0], acc0, 0, 0, 0);
            acc1 = __builtin_amdgcn_mfma_f32_16x16x32_bf16(A, Bf[s * 2 + 1], acc1, 0, 0, 0);
        }
        acc0s[T] = acc0;
        acc1s[T] = acc1;
    }
    __syncthreads();   // staging reads done -> lmsg may alias

    // ---- C-write: col = n (+16 for acc1), row = base + quad*4 + r ----
#pragma unroll
    for (int T = 0; T < 4; ++T) {
        int base = w * 64 + T * 16;
#pragma unroll
        for (int r = 0; r < 4; ++r) {
            int row = base + quad * 4 + r;
            lmsg[row * N_OUTC + n] = acc0s[T][r];
            if (n < 4) lmsg[row * N_OUTC + 16 + n] = acc1s[T][r];
        }
    }
    __syncthreads();

    // ---- R1: segmented reduce; fused root+bias+relu for fast rows ----
    int r0 = rbounds[0], r1 = rbounds[1];
    int nrows = r1 - r0 + 1;
    int work = nrows * 5;
    for (int ww = t; ww < work; ww += 256) {
        int idx = ww / 5;
        int q = ww - idx * 5;
        int row = r0 + idx;
        int a0 = rowptr[row], a1 = rowptr[row + 1];
        int s0 = max(a0, j0), s1 = min(a1, jend);
        float ac0 = 0.f, ac1 = 0.f, ac2 = 0.f, ac3 = 0.f;
        for (int s = s0; s < s1; ++s) {
            const float4 v = *(const float4*)&lmsg[(s - j0) * N_OUTC + q * 4];
            ac0 += v.x; ac1 += v.y; ac2 += v.z; ac3 += v.w;
        }
        bool owned = (a0 >= j0 && a1 <= jend);
        if (owned && idx < CAP) {
            const float4* xp = (const float4*)&x[(size_t)row * F_INN];
            float4 xa = xp[0], xb4 = xp[1];
            float rx[F_INN] = {xa.x, xa.y, xa.z, xa.w, xb4.x, xb4.y, xb4.z, xb4.w};
            float av[4] = {ac0, ac1, ac2, ac3};
#pragma unroll
            for (int u = 0; u < 4; ++u) {
                int oc = q * 4 + u;
                float a = av[u] + eb[oc];
#pragma unroll
                for (int f = 0; f < F_INN; ++f)
                    a = fmaf(rx[f], root[f * N_OUTC + oc], a);
                x1buf[idx * N_OUTC + oc] = fmaxf(a, 0.0f);
            }
        } else {
            float* dst = &agg[(size_t)row * N_OUTC + q * 4];
            if (owned) {
                *(float4*)dst = make_float4(ac0, ac1, ac2, ac3);
            } else {
                unsafeAtomicAdd(dst + 0, ac0);
                unsafeAtomicAdd(dst + 1, ac1);
                unsafeAtomicAdd(dst + 2, ac2);
                unsafeAtomicAdd(dst + 3, ac3);
            }
        }
    }
    __syncthreads();

    // ---- R2: hws1 = bf16(dinv * (x1 @ g1w)) for fast rows ----
    int fast = min(nrows, CAP);
    int work2 = fast * 8;
    for (int ww = t; ww < work2; ww += 256) {
        int idx = ww >> 3;
        int qc = ww & 7;
        int row = r0 + idx;
        int a0 = rowptr[row], a1 = rowptr[row + 1];
        if (!(a0 >= j0 && a1 <= jend)) continue;
        float di = rsqrtf((float)(a1 - a0) + 1.0f);
        float m0 = 0.f, m1 = 0.f, m2 = 0.f, m3 = 0.f;
        const float* xr = &x1buf[idx * N_OUTC];
#pragma unroll
        for (int o = 0; o < N_OUTC; ++o) {
            float xv = xr[o];
            const float4 g = *(const float4*)&g1w[o * G_DIM + qc * 4];
            m0 = fmaf(xv, g.x, m0); m1 = fmaf(xv, g.y, m1);
            m2 = fmaf(xv, g.z, m2); m3 = fmaf(xv, g.w, m3);
        }
        unsigned lo32 = (unsigned)f2bf(m0 * di) | ((unsigned)f2bf(m1 * di) << 16);
        unsigned hi32 = (unsigned)f2bf(m2 * di) | ((unsigned)f2bf(m3 * di) << 16);
        *(uint2*)&hws1[(size_t)row * G_DIM + qc * 4] = make_uint2(lo32, hi32);
    }
}

// ---------------------------------------------------------------------------
// 5) Cleanup: node transform for rows NOT handled by ECC's fast path
//    (boundary, beyond-CAP, block-edge empty rows). ~12% of nodes.
// ---------------------------------------------------------------------------
__global__ __launch_bounds__(256) void cleanup_kernel(
    const float* __restrict__ agg, const float* __restrict__ x,
    const int* __restrict__ rowptr, int N,
    const float* __restrict__ root, const float* __restrict__ eb,
    const float* __restrict__ g1w,
    unsigned short* __restrict__ hws1)
{
    int n = blockIdx.x * 256 + threadIdx.x;
    if (n >= N) return;
    int a0 = rowptr[n], a1 = rowptr[n + 1];
    bool contained = (a1 > a0) ? ((a0 >> 8) == ((a1 - 1) >> 8))
                               : ((a0 & 255) != 0);
    if (contained) {
        // r0 of the covering block (must match ECC's rbounds[0])
        int target = (a0 >> 8) << 8;
        int lo = 0, hi = N - 1;
        while (lo < hi) {
            int m = (lo + hi + 1) >> 1;
            if (rowptr[m] <= target) lo = m; else hi = m - 1;
        }
        if (n - lo < CAP) return;          // handled inside ECC
    }

    const float4* xp = (const float4*)&x[(size_t)n * F_INN];
    float4 xa = xp[0], xb = xp[1];
    float xf[F_INN] = {xa.x, xa.y, xa.z, xa.w, xb.x, xb.y, xb.z, xb.w};

    float x1[N_OUTC];
#pragma unroll
    for (int o = 0; o < N_OUTC; ++o) {
        float a = agg[(size_t)n * N_OUTC + o] + eb[o];
#pragma unroll
        for (int f = 0; f < F_INN; ++f) a = fmaf(xf[f], root[f * N_OUTC + o], a);
        x1[o] = fmaxf(a, 0.0f);
    }

    float di = rsqrtf((float)(a1 - a0) + 1.0f);
#pragma unroll
    for (int q = 0; q < 4; ++q) {
        short8 o8;
#pragma unroll
        for (int u = 0; u < 8; ++u) {
            int g = q * 8 + u;
            float a = 0.0f;
#pragma unroll
            for (int o = 0; o < N_OUTC; ++o) a = fmaf(x1[o], g1w[o * G_DIM + g], a);
            o8[u] = (short)f2bf(a * di);
        }
        *(short8*)&hws1[(size_t)n * G_DIM + q * 8] = o8;
    }
}

// ---------------------------------------------------------------------------
// 6) GCN gather on pre-scaled bf16 features. Thread = (node, chunk of 4).
// ---------------------------------------------------------------------------
template<bool DO_MATMUL>
__global__ __launch_bounds__(256) void gcn_gather_kernel(
    const unsigned short* __restrict__ hws, const int* __restrict__ rowptr,
    const int* __restrict__ col_sorted, const float* __restrict__ dinv, int N,
    const float* __restrict__ bias, const float* __restrict__ w2,
    unsigned short* __restrict__ outbuf)
{
    __shared__ float x2s[64][33];
    __shared__ float w2s[G_DIM * G_DIM];

    int t = threadIdx.x;
    int nl = t >> 2;
    int q = t & 3;
    int n = blockIdx.x * 64 + nl;

    if (DO_MATMUL) {
        ((float4*)w2s)[t] = ((const float4*)w2)[t];
    }

    float xo[8];
    float di = 0.0f;
    if (n < N) {
        di = dinv[n];
        int j0 = rowptr[n], j1 = rowptr[n + 1];
        short8 sv = *(const short8*)&hws[(size_t)n * G_DIM + q * 8];
        float s[8];
#pragma unroll
        for (int k = 0; k < 8; ++k) s[k] = bf2f((unsigned short)sv[k]);
#pragma unroll 2
        for (int j = j0; j < j1; ++j) {
            int c = col_sorted[j];
            short8 v = *(const short8*)&hws[(size_t)c * G_DIM + q * 8];
#pragma unroll
            for (int k = 0; k < 8; ++k) s[k] += bf2f((unsigned short)v[k]);
        }
#pragma unroll
        for (int k = 0; k < 8; ++k)
            xo[k] = fmaxf(fmaf(di, s[k], bias[q * 8 + k]), 0.0f);
    } else {
#pragma unroll
        for (int k = 0; k < 8; ++k) xo[k] = 0.0f;
    }

    if (DO_MATMUL) {
#pragma unroll
        for (int k = 0; k < 8; ++k) x2s[nl][q * 8 + k] = xo[k];
        __syncthreads();
        if (n < N) {
            float a[8];
#pragma unroll
            for (int k = 0; k < 8; ++k) a[k] = 0.0f;
#pragma unroll
            for (int g = 0; g < G_DIM; ++g) {
                float xv = x2s[nl][g];
#pragma unroll
                for (int k = 0; k < 8; ++k)
                    a[k] = fmaf(xv, w2s[g * G_DIM + q * 8 + k], a[k]);
            }
            short8 o8;
#pragma unroll
            for (int k = 0; k < 8; ++k) o8[k] = (short)f2bf(a[k] * di);
            *(short8*)&outbuf[(size_t)n * G_DIM + q * 8] = o8;
        }
    } else {
        if (n < N) {
            short8 o8;
#pragma unroll
            for (int k = 0; k < 8; ++k) o8[k] = (short)f2bf(xo[k]);
            *(short8*)&outbuf[(size_t)n * G_DIM + q * 8] = o8;
        }
    }
}

// ---------------------------------------------------------------------------
// 7) Pool + head fused (x3 is bf16)
// ---------------------------------------------------------------------------
__global__ __launch_bounds__(256) void pool_head_kernel(
    const unsigned short* __restrict__ x3, const int* __restrict__ seg, int N,
    const float* __restrict__ d1w, const float* __restrict__ d1b,
    const float* __restrict__ d2w, const float* __restrict__ d2b,
    float* __restrict__ out)
{
    __shared__ float red[8][G_DIM];
    __shared__ float pvec[G_DIM];
    __shared__ int bounds[2];
    int g = blockIdx.x;
    int t = threadIdx.x;
    if (t < 2) {
        int target = g + t;
        int lo = 0, hi = N;
        while (lo < hi) {
            int m = (lo + hi) >> 1;
            if (seg[m] < target) lo = m + 1; else hi = m;
        }
        bounds[t] = lo;
    }
    __syncthreads();
    int n0 = bounds[0], n1 = bounds[1];
    int ch = t & (G_DIM - 1);
    int slice = t >> 5;
    float a = 0.0f;
    for (int n = n0 + slice; n < n1; n += 8)
        a += bf2f(x3[(size_t)n * G_DIM + ch]);
    red[slice][ch] = a;
    __syncthreads();
    if (slice == 0) {
        float s = red[0][ch];
#pragma unroll
        for (int k = 1; k < 8; ++k) s += red[k][ch];
        pvec[ch] = s;
    }
    __syncthreads();
    if (t < 64) {
        float acc = 0.0f;
        if (t < D1_DIM) {
            float tj = d1b[t];
#pragma unroll
            for (int gg = 0; gg < G_DIM; ++gg)
                tj = fmaf(pvec[gg], d1w[gg * D1_DIM + t], tj);
            acc = tj * d2w[t];
        }
#pragma unroll
        for (int d = 1; d < D1_DIM; d <<= 1) acc += __shfl_down(acc, d, 64);
        if (t == 0) out[g] = acc + d2b[0];
    }
}

// ---------------------------------------------------------------------------
extern "C" void kernel_launch(void* const* d_in, const int* in_sizes, int n_in,
                              void* d_out, int out_size, void* d_ws, size_t ws_size,
                              hipStream_t stream)
{
    const float* x    = (const float*)d_in[0];
    const float* e    = (const float*)d_in[1];
    const int*   ei   = (const int*)d_in[2];
    const int*   seg  = (const int*)d_in[3];
    const float* w1   = (const float*)d_in[4];
    const float* b1   = (const float*)d_in[5];
    const float* w2   = (const float*)d_in[6];
    const float* b2   = (const float*)d_in[7];
    const float* w3   = (const float*)d_in[8];
    const float* b3   = (const float*)d_in[9];
    const float* root = (const float*)d_in[10];
    const float* eb   = (const float*)d_in[11];
    const float* g1w  = (const float*)d_in[12];
    const float* g1b  = (const float*)d_in[13];
    const float* g2w  = (const float*)d_in[14];
    const float* g2b  = (const float*)d_in[15];
    const float* d1w  = (const float*)d_in[16];
    const float* d1b  = (const float*)d_in[17];
    const float* d2w  = (const float*)d_in[18];
    const float* d2b  = (const float*)d_in[19];

    const int N = in_sizes[3];            // 50000
    const int E = in_sizes[1] / S_DIM;    // 800000
    float* out = (float*)d_out;

    const int nbl = (N + 255) / 256;      // 196 (<= 256 for scanC)
    const int ebl = (E + 255) / 256;

    char* ws = (char*)d_ws;
    size_t off = 0;
    auto alloc = [&](size_t elems) -> char* {
        char* p = ws + off;
        off += ((elems * 4 + 15) & ~(size_t)15);
        return p;
    };
    int*   cnt        = (int*)  alloc(N);                    // zeroed (deg)
    float* agg        = (float*)alloc((size_t)N * N_OUTC);   // zeroed
    size_t zero_bytes = off;
    int*   rowptr     = (int*)  alloc(N + 1);
    int*   bsum       = (int*)  alloc(nbl);
    float* dinv       = (float*)alloc(N);
    int*   loc        = (int*)  alloc(E);
    int*   col_sorted = (int*)  alloc(E);
    unsigned short* B3f = (unsigned short*)alloc(6144 / 2);  // 12.3 KB
    int4*  e_sorted   = (int4*) alloc((size_t)E * 4);        // 16 B/edge
    unsigned short* hws1 = (unsigned short*)alloc((size_t)N * G_DIM / 2);
    unsigned short* hws2 = (unsigned short*)alloc((size_t)N * G_DIM / 2);
    unsigned short* x3   = (unsigned short*)alloc((size_t)N * G_DIM / 2);
    (void)ws_size;

    hipMemsetAsync(d_ws, 0, zero_bytes, stream);

    prep_kernel<<<24, 256, 0, stream>>>(w3, b3, B3f);
    loc_kernel<<<ebl, 256, 0, stream>>>(ei, E, cnt, loc);
    scanA_kernel<<<nbl, 256, 0, stream>>>(cnt, N, bsum);
    scanC_kernel<<<nbl, 256, 0, stream>>>(cnt, N, bsum, nbl, E, rowptr, dinv);
    build_kernel<<<ebl, 256, 0, stream>>>(ei, E, e, rowptr, loc, e_sorted);
    ecc_mfma_kernel<<<ebl, 256, 0, stream>>>(e_sorted, x, rowptr, N, E, B3f,
                                             w1, b1, w2, b2, root, eb, g1w,
                                             agg, col_sorted, hws1);
    cleanup_kernel<<<nbl, 256, 0, stream>>>(agg, x, rowptr, N, root, eb, g1w, hws1);
    gcn_gather_kernel<true><<<(N + 63) / 64, 256, 0, stream>>>(
        hws1, rowptr, col_sorted, dinv, N, g1b, g2w, hws2);
    gcn_gather_kernel<false><<<(N + 63) / 64, 256, 0, stream>>>(
        hws2, rowptr, col_sorted, dinv, N, g2b, nullptr, x3);
    pool_head_kernel<<<NGRAPH, 256, 0, stream>>>(x3, seg, N, d1w, d1b, d2w, d2b, out);
}